// Round 1
// baseline (184.256 us; speedup 1.0000x reference)
//
#include <hip/hip_runtime.h>

// Blockwise 16x16 2D DCT: out_tile = K @ T @ K^T, fp32, memory-bound.
// One 256-thread block handles a strip of 16 rows x 512 cols (32 tiles).
// LDS reused: phase A = input strip [16][516], phase B = U tiles [32][16][17].

#define IMG_W 1024
#define STRIP_COLS 512
#define LDS1_STRIDE 516   // 512 + 4 pad, keeps float4 alignment (516*4 % 16 == 0)
#define LDS2_TILE 272     // 16 rows * 17
#define LDS2_STRIDE 17    // +1 pad: odd stride -> 16 distinct banks on row reads

__global__ __launch_bounds__(256, 4) void dct16_kernel(
    const float* __restrict__ x,
    const float* __restrict__ kern,   // 16x16 DCT matrix, row-major
    float* __restrict__ out)
{
    __shared__ float lds[8704];       // max(16*516=8256, 32*272=8704) floats = 34816 B

    const int tid = threadIdx.x;
    const int blk = blockIdx.x;
    const int img = blk >> 7;         // 128 strips per 1024x1024 image
    const int s   = blk & 127;
    const int row_band = s >> 1;      // 64 bands of 16 rows
    const int col_half = s & 1;       // 2 halves of 512 cols
    const size_t base = ((size_t)img << 20)
                      + (size_t)(row_band << 4) * IMG_W
                      + (size_t)(col_half * STRIP_COLS);

    // ---- Phase A: coalesced load of strip into LDS --------------------------
    // 16 rows x 512 floats = 2048 float4; 256 threads x 8 iters.
    #pragma unroll
    for (int it = 0; it < 8; ++it) {
        int idx = it * 256 + tid;
        int row = idx >> 7;           // 128 float4 per row
        int c4  = idx & 127;
        float4 v = *reinterpret_cast<const float4*>(x + base + (size_t)row * IMG_W + c4 * 4);
        *reinterpret_cast<float4*>(&lds[row * LDS1_STRIDE + c4 * 4]) = v;
    }
    __syncthreads();

    // ---- Pass 1: U = K @ T, thread handles 2 adjacent columns ---------------
    {
        const int tile = tid >> 3;          // 32 tiles
        const int cl   = (tid & 7) * 2;     // local cols cl, cl+1

        float t0[16], t1[16], u0[16], u1[16];
        #pragma unroll
        for (int j = 0; j < 16; ++j) {
            const float* p = &lds[j * LDS1_STRIDE + tile * 16 + cl];
            t0[j] = p[0];
            t1[j] = p[1];
        }
        #pragma unroll
        for (int i = 0; i < 16; ++i) { u0[i] = 0.0f; u1[i] = 0.0f; }

        #pragma unroll
        for (int j = 0; j < 16; ++j) {
            #pragma unroll
            for (int i = 0; i < 16; ++i) {
                float kv = kern[i * 16 + j];   // uniform index -> s_load
                u0[i] += kv * t0[j];
                u1[i] += kv * t1[j];
            }
        }

        __syncthreads();  // all lds1 reads done before overwrite

        // store U row-major per tile, padded stride 17
        #pragma unroll
        for (int i = 0; i < 16; ++i) {
            lds[tile * LDS2_TILE + i * LDS2_STRIDE + cl]     = u0[i];
            lds[tile * LDS2_TILE + i * LDS2_STRIDE + cl + 1] = u1[i];
        }
    }
    __syncthreads();

    // ---- Pass 2: out = U @ K^T, thread handles 2 tile-rows ------------------
    #pragma unroll
    for (int pp = 0; pp < 2; ++pp) {
        const int p    = pp * 256 + tid;    // 512 (tile,row) pairs
        const int tile = p >> 4;
        const int r    = p & 15;

        float ur[16];
        #pragma unroll
        for (int l = 0; l < 16; ++l)
            ur[l] = lds[tile * LDS2_TILE + r * LDS2_STRIDE + l];

        float o[16];
        #pragma unroll
        for (int m = 0; m < 16; ++m) {
            float acc = 0.0f;
            #pragma unroll
            for (int l = 0; l < 16; ++l)
                acc += ur[l] * kern[m * 16 + l];   // uniform -> s_load
            o[m] = acc;
        }

        // thread owns 16 contiguous output floats (row r of its tile)
        float* gout = out + base + (size_t)r * IMG_W + tile * 16;
        #pragma unroll
        for (int q = 0; q < 4; ++q) {
            *reinterpret_cast<float4*>(gout + q * 4) =
                make_float4(o[q * 4], o[q * 4 + 1], o[q * 4 + 2], o[q * 4 + 3]);
        }
    }
}

extern "C" void kernel_launch(void* const* d_in, const int* in_sizes, int n_in,
                              void* d_out, int out_size, void* d_ws, size_t ws_size,
                              hipStream_t stream) {
    const float* x    = (const float*)d_in[0];
    const float* kern = (const float*)d_in[1];
    float* out        = (float*)d_out;

    const int n_img  = in_sizes[0] / (IMG_W * IMG_W);   // 96 images of 1024x1024
    const int blocks = n_img * 128;                     // 128 strips per image

    dct16_kernel<<<blocks, 256, 0, stream>>>(x, kern, out);
}

// Round 3
// 174.509 us; speedup vs baseline: 1.0559x; 1.0559x over previous
//
#include <hip/hip_runtime.h>

// Blockwise 16x16 2D DCT (out = K @ T @ K^T), fp32, memory-bound.
// Persistent blocks, double-buffered global_load_lds prefetch, raw s_barrier
// with counted vmcnt so prefetch loads stay in flight across barriers.
// Strip = 16 rows x 256 cols (16 tiles). 768 blocks x 256 threads, 3 blocks/CU.

#define IMG_W    1024
#define SCOLS    256
#define INSTRIDE 260          // floats per LDS row (+4 pad, keeps 16B align)
#define INBUF    4160         // 16*260 floats per in/out buffer
#define USTRIDE  20           // U row stride (80B: 16B-aligned)
#define UTILE    328          // floats per tile in U: 16*20+8 -> tiles offset 8 banks
#define UOFF     8320         // 2*INBUF
#define LDS_FLOATS 13568      // 2*4160 + 16*328 = 54272 B -> 3 blocks/CU

__device__ __forceinline__ void gload_lds16(const float* gp, float* lp) {
    // async 16B/lane global->LDS; LDS dest = wave-uniform base + lane*16
    __builtin_amdgcn_global_load_lds(
        (const __attribute__((address_space(1))) void*)gp,
        (__attribute__((address_space(3))) void*)lp,
        16, 0, 0);
}

__global__ __launch_bounds__(256, 3) void dct16_kernel(
    const float* __restrict__ x,
    const float* __restrict__ kern,      // 16x16 DCT matrix, row-major
    float* __restrict__ out,
    int strips_per_block, int total_strips)
{
    __shared__ float lds[LDS_FLOATS];

    const int tid  = threadIdx.x;
    const int lane = tid & 63;
    const int wid  = tid >> 6;

    int s0 = blockIdx.x * strips_per_block;
    if (s0 >= total_strips) return;
    int ns = strips_per_block;
    if (s0 + ns > total_strips) ns = total_strips - s0;

    // strip s -> memory base: row band (s>>2), col quarter (s&3)
    auto strip_base = [](int s) -> size_t {
        return (size_t)(s >> 2) * (16 * IMG_W) + (size_t)(s & 3) * SCOLS;
    };

    // issue 4 DMA instructions per wave: whole 16x256 strip into buffer b
    auto dma_strip = [&](int s, int b) {
        const float* gbase = x + strip_base(s);
        float*       lbase = &lds[b * INBUF];
        #pragma unroll
        for (int it = 0; it < 4; ++it) {
            int row = it * 4 + wid;                  // wave-uniform
            gload_lds16(gbase + (size_t)row * IMG_W + lane * 4,
                        lbase + row * INSTRIDE);
        }
    };

    dma_strip(s0, 0);   // prologue: strip 0 in flight (4 vm-ops/wave)

    for (int k = 0; k < ns; ++k) {
        const int cur = k & 1;
        if (k + 1 < ns) dma_strip(s0 + k + 1, cur ^ 1);

        // Wait for strip k's DMA. Per-wave vm queue (issue order):
        //   [DMA_k(4)] [stores_{k-1}(4) if k>0] [DMA_{k+1}(4) if issued]
        if (k == 0) {
            if (ns > 1) { asm volatile("s_waitcnt vmcnt(4)" ::: "memory"); }
            else        { asm volatile("s_waitcnt vmcnt(0)" ::: "memory"); }
        } else if (k + 1 < ns) {
            asm volatile("s_waitcnt vmcnt(8)" ::: "memory");
        } else {
            asm volatile("s_waitcnt vmcnt(4)" ::: "memory");
        }
        __builtin_amdgcn_s_barrier();
        asm volatile("" ::: "memory");

        const float* ibuf = &lds[cur * INBUF];

        // ---- Pass 1: U = K @ T. Thread = one column c of the strip. ----
        {
            const int c = tid;
            const int t = c >> 4;
            const int cl = c & 15;
            float tv[16];
            #pragma unroll
            for (int j = 0; j < 16; ++j) tv[j] = ibuf[j * INSTRIDE + c];

            float u[16];
            #pragma unroll
            for (int i = 0; i < 16; ++i) u[i] = 0.0f;
            #pragma unroll
            for (int j = 0; j < 16; ++j) {
                float tj = tv[j];
                #pragma unroll
                for (int i = 0; i < 16; ++i)
                    u[i] = fmaf(kern[i * 16 + j], tj, u[i]);
            }

            float* ubase = &lds[UOFF + t * UTILE];
            #pragma unroll
            for (int i = 0; i < 16; ++i)
                ubase[i * USTRIDE + cl] = u[i];
        }
        asm volatile("s_waitcnt lgkmcnt(0)" ::: "memory");
        __builtin_amdgcn_s_barrier();
        asm volatile("" ::: "memory");

        // ---- Pass 2: out = U @ K^T. Thread = (tile, row). -------------
        {
            const int t = tid >> 4;
            const int r = tid & 15;
            const float* ubase = &lds[UOFF + t * UTILE + r * USTRIDE];

            float ur[16];
            #pragma unroll
            for (int p = 0; p < 4; ++p) {
                float4 v = *reinterpret_cast<const float4*>(ubase + p * 4);
                ur[p * 4 + 0] = v.x; ur[p * 4 + 1] = v.y;
                ur[p * 4 + 2] = v.z; ur[p * 4 + 3] = v.w;
            }

            float o[16];
            #pragma unroll
            for (int m = 0; m < 16; ++m) {
                float acc = 0.0f;
                #pragma unroll
                for (int l = 0; l < 16; ++l)
                    acc = fmaf(ur[l], kern[m * 16 + l], acc);
                o[m] = acc;
            }

            // stage to out buffer = current input buffer (dead after pass 1)
            float* obase = &lds[cur * INBUF + r * INSTRIDE + t * 16];
            #pragma unroll
            for (int f = 0; f < 4; ++f)
                *reinterpret_cast<float4*>(obase + f * 4) =
                    make_float4(o[f*4+0], o[f*4+1], o[f*4+2], o[f*4+3]);
        }
        asm volatile("s_waitcnt lgkmcnt(0)" ::: "memory");
        __builtin_amdgcn_s_barrier();
        asm volatile("" ::: "memory");

        // ---- Coalesced store: wave-contiguous 1KB float4 runs ---------
        {
            const size_t base = strip_base(s0 + k);
            const float* obuf = &lds[cur * INBUF];
            #pragma unroll
            for (int it = 0; it < 4; ++it) {
                int idx = it * 256 + tid;
                int row = idx >> 6;
                int c4  = idx & 63;
                float4 v = *reinterpret_cast<const float4*>(obuf + row * INSTRIDE + c4 * 4);
                *reinterpret_cast<float4*>(out + base + (size_t)row * IMG_W + c4 * 4) = v;
            }
        }
        // staging reads must complete before next iter's DMA overwrites buf[cur]
        asm volatile("s_waitcnt lgkmcnt(0)" ::: "memory");
        __builtin_amdgcn_s_barrier();
        asm volatile("" ::: "memory");
    }
}

extern "C" void kernel_launch(void* const* d_in, const int* in_sizes, int n_in,
                              void* d_out, int out_size, void* d_ws, size_t ws_size,
                              hipStream_t stream) {
    const float* x    = (const float*)d_in[0];
    const float* kern = (const float*)d_in[1];
    float* out        = (float*)d_out;

    const int n_img        = in_sizes[0] / (IMG_W * IMG_W);   // 96
    const int total_strips = n_img * 256;                     // 64 bands * 4 quarters
    const int blocks       = 768;                             // 3 per CU
    const int per_block    = (total_strips + blocks - 1) / blocks;

    dct16_kernel<<<blocks, 256, 0, stream>>>(x, kern, out, per_block, total_strips);
}